// Round 6
// baseline (525.078 us; speedup 1.0000x reference)
//
#include <hip/hip_runtime.h>

// B=131072, T=16, D=2, H=64. 16 rows/wave, 4 waves/block.
// R6 = R5 + bounds(256,4) (16 waves/CU; VGPR cap 128 vs demand ~92, LDS 38400*4=153.6K<=160K)
//        + r/z biases folded into MFMA C-init (saves 2 adds/element).
#define BSZ 131072
#define TT  16
#define RPB 64
#define BLK 256

#define NEG_LOG2E  (-1.4426950408889634f)
#define TWO_LOG2E  2.8853900817779268f

typedef __bf16 bf16x8 __attribute__((ext_vector_type(8)));
typedef float  f32x4  __attribute__((ext_vector_type(4)));

#define MFMA(a,b,c) __builtin_amdgcn_mfma_f32_16x16x32_bf16((a),(b),(c),0,0,0)

static __device__ __forceinline__ float rcp_f(float v){ float r; asm("v_rcp_f32 %0, %1" : "=v"(r) : "v"(v)); return r; }
static __device__ __forceinline__ float exp2_f(float v){ float r; asm("v_exp_f32 %0, %1" : "=v"(r) : "v"(v)); return r; }

__global__ __launch_bounds__(BLK, 4) void flow6(
    const float* __restrict__ x,     // (B,16,2)
    const float* __restrict__ z,     // (B,64)
    const float* __restrict__ W_ih,  // (192,2)
    const float* __restrict__ W_hh,  // (192,64)
    const float* __restrict__ b_ih,  // (192)
    const float* __restrict__ b_hh,  // (192)
    const float* __restrict__ W1,    // (64,32)
    const float* __restrict__ b1,    // (32)
    const float* __restrict__ W2,    // (32,4)
    const float* __restrict__ b2,    // (4)
    float* __restrict__ y_out,       // (B,16,2)
    float* __restrict__ lad_out)     // (B)
{
  // LDS: 16384 + 4096 + 3072 + 9216 + 5120 + 512 = 38400 B (4 blocks/CU fits 160K)
  __shared__ __align__(16) __bf16 whhtab[16*64*8];  // z/n-gate B-frags [f][lane][8] (pre-scaled)
  __shared__ __align__(16) __bf16 w1tab[4*64*8];    // W1 B-frags
  __shared__ __align__(16) float4 gi_tab[192];      // {Wih0*sc, Wih1*sc, b_ih_n*sc (n only), 0}
  __shared__ __align__(16) __bf16 hbuf[RPB*72];     // h bf16, stride 72
  __shared__ __align__(16) __bf16 hidbuf[RPB*40];   // hidden, stride 40; cols 32..39 = ls
  __shared__ __align__(16) float  ystate[RPB*2];    // y_{t-1} [row][comp]

  const int tid  = threadIdx.x;
  const int lane = tid & 63, wave = tid >> 6;
  const int quad = lane >> 4, n16 = lane & 15;
  const int gb   = blockIdx.x * RPB;
  const f32x4 zero = {0.f,0.f,0.f,0.f};

  // ---------- one-time staging ----------
  if (tid < 192) {  // gi_tab, pre-scaled; r/z bias NOT here (goes to C-init)
    const int j = tid;
    const float sc = (j < 128) ? NEG_LOG2E : TWO_LOG2E;
    const float w0 = W_ih[2*j]*sc, w1 = W_ih[2*j+1]*sc;
    gi_tab[j] = make_float4(w0, w1, (j < 128) ? 0.f : b_ih[j]*sc, 0.f);
  }
  // whhtab: f = (gate-1)*8 + g*2 + kt, gate 1=z (x -log2e), 2=n (x 2log2e)
  #pragma unroll
  for (int i = 0; i < 4; ++i) {
    const int f = i*4 + wave;
    const int gate = 1 + (f >> 3), g = (f >> 1) & 3, kt = f & 1;
    const float sc = (gate == 1) ? NEG_LOG2E : TWO_LOG2E;
    const float* p = W_hh + (size_t)((gate*4 + g)*16 + n16)*64 + kt*32 + quad*8;
    bf16x8 v;
    #pragma unroll
    for (int j = 0; j < 8; ++j) v[j] = (__bf16)(p[j]*sc);
    *(bf16x8*)&whhtab[(f*64 + lane)*8] = v;
  }
  { // w1tab: frag f = c2*2+kt, one per wave (unscaled)
    const int f = wave, c2 = f >> 1, kt = f & 1;
    bf16x8 v;
    #pragma unroll
    for (int j = 0; j < 8; ++j)
      v[j] = (__bf16)W1[(size_t)(kt*32 + quad*8 + j)*32 + c2*16 + n16];
    *(bf16x8*)&w1tab[(f*64 + lane)*8] = v;
  }
  if (tid < 128) ystate[tid] = 0.f;
  #pragma unroll
  for (int r4 = 0; r4 < 4; ++r4) {  // z -> hbuf (bf16)
    const int row = (tid >> 4) + r4*16, col = (tid & 15)*4;
    const float4 zv = *(const float4*)&z[(size_t)(gb + row)*64 + col];
    hbuf[row*72 + col+0] = (__bf16)zv.x; hbuf[row*72 + col+1] = (__bf16)zv.y;
    hbuf[row*72 + col+2] = (__bf16)zv.z; hbuf[row*72 + col+3] = (__bf16)zv.w;
  }

  // r-gate B-frags in regs (pre-scaled): 8 x bf16x8 = 32 VGPR
  bf16x8 Whr[4][2];
  #pragma unroll
  for (int g = 0; g < 4; ++g)
    #pragma unroll
    for (int kt = 0; kt < 2; ++kt) {
      const float* p = W_hh + (size_t)(g*16 + n16)*64 + kt*32 + quad*8;
      bf16x8 v;
      #pragma unroll
      for (int j = 0; j < 8; ++j) v[j] = (__bf16)(p[j]*NEG_LOG2E);
      Whr[g][kt] = v;
    }
  // W2 B-frag in regs (4 VGPR)
  bf16x8 W2f;
  #pragma unroll
  for (int j = 0; j < 8; ++j)
    W2f[j] = (n16 < 4) ? (__bf16)W2[(size_t)(quad*8 + j)*4 + n16] : (__bf16)0.f;

  // h state fp32 C-layout
  f32x4 hst[4];
  #pragma unroll
  for (int g = 0; g < 4; ++g)
    #pragma unroll
    for (int i = 0; i < 4; ++i)
      hst[g][i] = z[(size_t)(gb + wave*16 + quad*4 + i)*64 + g*16 + n16];
  // per-gate C-init biases (scaled): r,z = (b_ih+b_hh)*sc ; n = b_hh*sc
  float brr[4], brz[4], bhn[4];
  #pragma unroll
  for (int g = 0; g < 4; ++g) {
    const int c = g*16 + n16;
    brr[g] = (b_ih[c]       + b_hh[c]      )*NEG_LOG2E;
    brz[g] = (b_ih[64 + c]  + b_hh[64 + c] )*NEG_LOG2E;
    bhn[g] =                  b_hh[128 + c] *TWO_LOG2E;
  }
  const float b1v0 = b1[n16], b1v1 = b1[16 + n16];
  const float b2ln = (n16 < 4) ? b2[n16] : 0.f;

  __syncthreads();  // only barrier

  const int arow = wave*16 + n16;
  bf16x8 a0 = *(const bf16x8*)&hbuf[arow*72 + quad*8];
  bf16x8 a1 = *(const bf16x8*)&hbuf[arow*72 + 32 + quad*8];

  const int erow = wave*16 + (lane & 15);
  const int comp = (lane >> 4) & 1;
  const float* xp = x + (size_t)(gb + erow)*(TT*2) + comp;
  float*       yp = y_out + (size_t)(gb + erow)*(TT*2) + comp;
  float yc = 0.f, lad = 0.f;

  #pragma unroll 1
  for (int t = 0; t < TT; ++t) {
    const float xt = (lane < 32) ? xp[t*2] : 0.f;   // early global load
    float ys0[4], ys1[4];
    #pragma unroll
    for (int i = 0; i < 4; ++i) {
      const float2 yv = *(const float2*)&ystate[(wave*16 + quad*4 + i)*2];
      ys0[i] = yv.x; ys1[i] = yv.y;
    }

    // ---- GRU per col-group g ----
    #pragma unroll
    for (int g = 0; g < 4; ++g) {
      const bf16x8 bz0 = *(const bf16x8*)&whhtab[((g*2    )*64 + lane)*8];
      const bf16x8 bz1 = *(const bf16x8*)&whhtab[((g*2 + 1)*64 + lane)*8];
      const bf16x8 bn0 = *(const bf16x8*)&whhtab[((8 + g*2    )*64 + lane)*8];
      const bf16x8 bn1 = *(const bf16x8*)&whhtab[((8 + g*2 + 1)*64 + lane)*8];
      const f32x4 crinit = {brr[g], brr[g], brr[g], brr[g]};
      const f32x4 czinit = {brz[g], brz[g], brz[g], brz[g]};
      const f32x4 cninit = {bhn[g], bhn[g], bhn[g], bhn[g]};
      f32x4 cr = MFMA(a0, Whr[g][0], crinit); cr = MFMA(a1, Whr[g][1], cr);
      f32x4 cz = MFMA(a0, bz0, czinit);       cz = MFMA(a1, bz1, cz);
      f32x4 cn = MFMA(a0, bn0, cninit);       cn = MFMA(a1, bn1, cn);
      const float4 Tr = gi_tab[      g*16 + n16];
      const float4 Tz = gi_tab[ 64 + g*16 + n16];
      const float4 Tn = gi_tab[128 + g*16 + n16];
      #pragma unroll
      for (int i = 0; i < 4; ++i) {
        const float sr  = fmaf(Tr.x, ys0[i], fmaf(Tr.y, ys1[i], cr[i]));  // -log2e * vr
        const float sz  = fmaf(Tz.x, ys0[i], fmaf(Tz.y, ys1[i], cz[i]));  // -log2e * vz
        const float gin = fmaf(Tn.x, ys0[i], fmaf(Tn.y, ys1[i], Tn.z));   // 2log2e * i_n
        const float r  = rcp_f(1.0f + exp2_f(sr));
        const float u  = rcp_f(1.0f + exp2_f(sz));
        const float pre = fmaf(r, cn[i], gin);                            // 2log2e * vn
        const float nn = fmaf(-2.0f, rcp_f(1.0f + exp2_f(pre)), 1.0f);    // tanh(vn)
        const float hv = fmaf(u, hst[g][i] - nn, nn);
        hst[g][i] = hv;
        hbuf[(wave*16 + quad*4 + i)*72 + g*16 + n16] = (__bf16)hv;
      }
    }

    a0 = *(const bf16x8*)&hbuf[arow*72 + quad*8];
    a1 = *(const bf16x8*)&hbuf[arow*72 + 32 + quad*8];

    // ---- MLP1 ----
    #pragma unroll
    for (int c2 = 0; c2 < 2; ++c2) {
      const float bb = c2 ? b1v1 : b1v0;
      const f32x4 binit = {bb, bb, bb, bb};
      f32x4 hc = MFMA(a0, *(const bf16x8*)&w1tab[((c2*2  )*64 + lane)*8], binit);
      hc       = MFMA(a1, *(const bf16x8*)&w1tab[((c2*2+1)*64 + lane)*8], hc);
      #pragma unroll
      for (int i = 0; i < 4; ++i)
        hidbuf[(wave*16 + quad*4 + i)*40 + c2*16 + n16] = (__bf16)fmaxf(hc[i], 0.f);
    }

    // ---- MLP2: ls -> hidbuf pad ----
    {
      const bf16x8 ha = *(const bf16x8*)&hidbuf[arow*40 + quad*8];
      const f32x4 b2init = {b2ln, b2ln, b2ln, b2ln};
      const f32x4 ls = MFMA(ha, W2f, b2init);
      if (n16 < 4) {
        #pragma unroll
        for (int i = 0; i < 4; ++i)
          ((float*)&hidbuf[(wave*16 + quad*4 + i)*40 + 32])[n16] = ls[i];
      }
    }

    // ---- epilogue (32 lanes), direct global y store ----
    if (lane < 32) {
      const float* lsp = (const float*)&hidbuf[erow*40 + 32];
      const float lc = lsp[comp];
      const float l2 = lsp[2 + comp];
      const float s  = __logf(1.0f + __expf(l2)) + 0.001f;
      yc += lc + s * xt;
      lad += __logf(s);
      ystate[erow*2 + comp] = yc;
      yp[t*2] = yc;
    }
  }

  const float lado = __shfl(lad, lane ^ 16, 64);
  if (lane < 16) lad_out[gb + wave*16 + lane] = lad + lado;
}

extern "C" void kernel_launch(void* const* d_in, const int* in_sizes, int n_in,
                              void* d_out, int out_size, void* d_ws, size_t ws_size,
                              hipStream_t stream) {
  const float* x    = (const float*)d_in[0];
  const float* z    = (const float*)d_in[1];
  const float* W_ih = (const float*)d_in[2];
  const float* W_hh = (const float*)d_in[3];
  const float* b_ih = (const float*)d_in[4];
  const float* b_hh = (const float*)d_in[5];
  const float* W1   = (const float*)d_in[6];
  const float* b1   = (const float*)d_in[7];
  const float* W2   = (const float*)d_in[8];
  const float* b2   = (const float*)d_in[9];

  float* y_out   = (float*)d_out;
  float* lad_out = y_out + (size_t)BSZ * TT * 2;

  dim3 grid(BSZ / RPB), block(BLK);
  hipLaunchKernelGGL(flow6, grid, block, 0, stream,
                     x, z, W_ih, W_hh, b_ih, b_hh, W1, b1, W2, b2,
                     y_out, lad_out);
}

// Round 8
// 309.434 us; speedup vs baseline: 1.6969x; 1.6969x over previous
//
#include <hip/hip_runtime.h>

// B=131072, T=16, D=2, H=64. 32 rows/wave (2 strips of 16), 4 waves/block (RPB=128).
// R8: bounds(256,2) -> 256 unified regs/wave: ALL Whh frags in regs (96), W1 in LDS,
// 2-strip ILP per wave. 2 blocks/CU (VGPR-limited), grid 1024 = exactly 2.0 rounds.
// Compiler memory fences at every cross-lane LDS handoff (R7 post-mortem).
#define BSZ 131072
#define TT  16
#define RPB 128
#define BLK 256

#define NEG_LOG2E  (-1.4426950408889634f)
#define TWO_LOG2E  2.8853900817779268f

typedef __bf16 bf16x8 __attribute__((ext_vector_type(8)));
typedef float  f32x4  __attribute__((ext_vector_type(4)));

#define MFMA(a,b,c) __builtin_amdgcn_mfma_f32_16x16x32_bf16((a),(b),(c),0,0,0)
// Compiler-level memory barrier: forbids reordering/forwarding of LDS ops across it.
// HW executes a wave's DS ops in order, so no s_waitcnt needed for same-wave handoff.
#define LDS_FENCE() asm volatile("" ::: "memory")

static __device__ __forceinline__ float rcp_f(float v){ float r; asm("v_rcp_f32 %0, %1" : "=v"(r) : "v"(v)); return r; }
static __device__ __forceinline__ float exp2_f(float v){ float r; asm("v_exp_f32 %0, %1" : "=v"(r) : "v"(v)); return r; }

__global__ __launch_bounds__(BLK, 2) void flow8(
    const float* __restrict__ x,     // (B,16,2)
    const float* __restrict__ z,     // (B,64)
    const float* __restrict__ W_ih,  // (192,2)
    const float* __restrict__ W_hh,  // (192,64)
    const float* __restrict__ b_ih,  // (192)
    const float* __restrict__ b_hh,  // (192)
    const float* __restrict__ W1,    // (64,32)
    const float* __restrict__ b1,    // (32)
    const float* __restrict__ W2,    // (32,4)
    const float* __restrict__ b2,    // (4)
    float* __restrict__ y_out,       // (B,16,2)
    float* __restrict__ lad_out)     // (B)
{
  // LDS: 4096 + 3072 + 18432 + 10240 + 1024 = 36864 B
  __shared__ __align__(16) __bf16 w1tab[4*64*8];    // W1 B-frags [f][lane][8]
  __shared__ __align__(16) float4 gi_tab[192];      // {Wih0*sc, Wih1*sc, b_ih_n*sc (n only), 0}
  __shared__ __align__(16) __bf16 hbuf[RPB*72];     // h bf16, stride 72
  __shared__ __align__(16) __bf16 hidbuf[RPB*40];   // hidden, stride 40; cols 32..39 = ls pad
  __shared__ __align__(16) float  ystate[RPB*2];    // y_{t-1} [row][comp]

  const int tid  = threadIdx.x;
  const int lane = tid & 63, wave = tid >> 6;
  const int quad = lane >> 4, n16 = lane & 15;
  const int gb   = blockIdx.x * RPB;
  const int wbase = wave * 32;                      // first row of this wave's 32-row strip pair

  // ---------- one-time staging ----------
  if (tid < 192) {  // gi_tab, pre-scaled; r/z biases live in C-init regs
    const int j = tid;
    const float sc = (j < 128) ? NEG_LOG2E : TWO_LOG2E;
    const float w0 = W_ih[2*j]*sc, w1 = W_ih[2*j+1]*sc;
    gi_tab[j] = make_float4(w0, w1, (j < 128) ? 0.f : b_ih[j]*sc, 0.f);
  }
  { // w1tab: frag f = c2*2+kt = wave
    const int f = wave, c2 = f >> 1, kt = f & 1;
    bf16x8 v;
    #pragma unroll
    for (int j = 0; j < 8; ++j)
      v[j] = (__bf16)W1[(size_t)(kt*32 + quad*8 + j)*32 + c2*16 + n16];
    *(bf16x8*)&w1tab[(f*64 + lane)*8] = v;
  }
  ystate[tid] = 0.f;                                 // 256 = RPB*2
  #pragma unroll
  for (int r8 = 0; r8 < 8; ++r8) {  // z -> hbuf (bf16), 128 rows
    const int row = (tid >> 4) + r8*16, col = (tid & 15)*4;
    const float4 zv = *(const float4*)&z[(size_t)(gb + row)*64 + col];
    hbuf[row*72 + col+0] = (__bf16)zv.x; hbuf[row*72 + col+1] = (__bf16)zv.y;
    hbuf[row*72 + col+2] = (__bf16)zv.z; hbuf[row*72 + col+3] = (__bf16)zv.w;
  }

  // ALL Whh B-frags in regs (pre-scaled): 24 x bf16x8 = 96 VGPR. ct = G*4+g (G:0=r,1=z,2=n)
  bf16x8 Whh[12][2];
  #pragma unroll
  for (int ct = 0; ct < 12; ++ct)
    #pragma unroll
    for (int kt = 0; kt < 2; ++kt) {
      const float sc = (ct < 8) ? NEG_LOG2E : TWO_LOG2E;
      const float* p = W_hh + (size_t)(ct*16 + n16)*64 + kt*32 + quad*8;
      bf16x8 v;
      #pragma unroll
      for (int j = 0; j < 8; ++j) v[j] = (__bf16)(p[j]*sc);
      Whh[ct][kt] = v;
    }
  // W2 B-frag in regs
  bf16x8 W2f;
  #pragma unroll
  for (int j = 0; j < 8; ++j)
    W2f[j] = (n16 < 4) ? (__bf16)W2[(size_t)(quad*8 + j)*4 + n16] : (__bf16)0.f;

  // h state fp32 C-layout, 2 strips: hst[s*4+g][i] = h[wbase + s*16 + quad*4+i][g*16+n16]
  f32x4 hst[8];
  #pragma unroll
  for (int s = 0; s < 2; ++s)
    #pragma unroll
    for (int g = 0; g < 4; ++g)
      #pragma unroll
      for (int i = 0; i < 4; ++i)
        hst[s*4+g][i] = z[(size_t)(gb + wbase + s*16 + quad*4 + i)*64 + g*16 + n16];
  // C-init biases (scaled)
  float brr[4], brz[4], bhn[4];
  #pragma unroll
  for (int g = 0; g < 4; ++g) {
    const int c = g*16 + n16;
    brr[g] = (b_ih[c]      + b_hh[c]      )*NEG_LOG2E;
    brz[g] = (b_ih[64 + c] + b_hh[64 + c] )*NEG_LOG2E;
    bhn[g] =                 b_hh[128 + c] *TWO_LOG2E;
  }
  const float b1v0 = b1[n16], b1v1 = b1[16 + n16];
  const float b2ln = (n16 < 4) ? b2[n16] : 0.f;

  __syncthreads();  // only block barrier

  bf16x8 a0[2], a1[2];
  #pragma unroll
  for (int s = 0; s < 2; ++s) {
    const int ar = wbase + s*16 + n16;
    a0[s] = *(const bf16x8*)&hbuf[ar*72 + quad*8];
    a1[s] = *(const bf16x8*)&hbuf[ar*72 + 32 + quad*8];
  }

  // epilogue mapping: all 64 lanes. s = lane>>5, comp = (lane>>4)&1, r16 = lane&15
  const int es   = lane >> 5;
  const int comp = (lane >> 4) & 1;
  const int erow = wbase + es*16 + (lane & 15);
  const float* xp = x + (size_t)(gb + erow)*(TT*2) + comp;
  float*       yp = y_out + (size_t)(gb + erow)*(TT*2) + comp;
  float yc = 0.f, lad = 0.f;

  #pragma unroll 1
  for (int t = 0; t < TT; ++t) {
    const float xt = xp[t*2];   // early global load (L2/L3-resident)

    // ---- GRU, both strips ----
    #pragma unroll
    for (int s = 0; s < 2; ++s) {
      float ys0[4], ys1[4];
      #pragma unroll
      for (int i = 0; i < 4; ++i) {
        const float2 yv = *(const float2*)&ystate[(wbase + s*16 + quad*4 + i)*2];
        ys0[i] = yv.x; ys1[i] = yv.y;
      }
      #pragma unroll
      for (int g = 0; g < 4; ++g) {
        const f32x4 crinit = {brr[g], brr[g], brr[g], brr[g]};
        const f32x4 czinit = {brz[g], brz[g], brz[g], brz[g]};
        const f32x4 cninit = {bhn[g], bhn[g], bhn[g], bhn[g]};
        f32x4 cr = MFMA(a0[s], Whh[g  ][0], crinit); cr = MFMA(a1[s], Whh[g  ][1], cr);
        f32x4 cz = MFMA(a0[s], Whh[4+g][0], czinit); cz = MFMA(a1[s], Whh[4+g][1], cz);
        f32x4 cn = MFMA(a0[s], Whh[8+g][0], cninit); cn = MFMA(a1[s], Whh[8+g][1], cn);
        const float4 Tr = gi_tab[      g*16 + n16];
        const float4 Tz = gi_tab[ 64 + g*16 + n16];
        const float4 Tn = gi_tab[128 + g*16 + n16];
        #pragma unroll
        for (int i = 0; i < 4; ++i) {
          const float sr  = fmaf(Tr.x, ys0[i], fmaf(Tr.y, ys1[i], cr[i]));  // -log2e*vr
          const float sz  = fmaf(Tz.x, ys0[i], fmaf(Tz.y, ys1[i], cz[i]));  // -log2e*vz
          const float gin = fmaf(Tn.x, ys0[i], fmaf(Tn.y, ys1[i], Tn.z));   // 2log2e*i_n
          const float r  = rcp_f(1.0f + exp2_f(sr));
          const float u  = rcp_f(1.0f + exp2_f(sz));
          const float pre = fmaf(r, cn[i], gin);                            // 2log2e*vn
          const float nn = fmaf(-2.0f, rcp_f(1.0f + exp2_f(pre)), 1.0f);    // tanh(vn)
          const float hv = fmaf(u, hst[s*4+g][i] - nn, nn);
          hst[s*4+g][i] = hv;
          hbuf[(wbase + s*16 + quad*4 + i)*72 + g*16 + n16] = (__bf16)hv;
        }
      }
    }
    LDS_FENCE();   // gate writes (C-layout) -> A-frag reads, cross-lane

    #pragma unroll
    for (int s = 0; s < 2; ++s) {
      const int ar = wbase + s*16 + n16;
      a0[s] = *(const bf16x8*)&hbuf[ar*72 + quad*8];
      a1[s] = *(const bf16x8*)&hbuf[ar*72 + 32 + quad*8];
    }

    // ---- MLP1, both strips ----
    #pragma unroll
    for (int s = 0; s < 2; ++s)
      #pragma unroll
      for (int c2 = 0; c2 < 2; ++c2) {
        const float bb = c2 ? b1v1 : b1v0;
        const f32x4 binit = {bb, bb, bb, bb};
        f32x4 hc = MFMA(a0[s], *(const bf16x8*)&w1tab[((c2*2  )*64 + lane)*8], binit);
        hc       = MFMA(a1[s], *(const bf16x8*)&w1tab[((c2*2+1)*64 + lane)*8], hc);
        #pragma unroll
        for (int i = 0; i < 4; ++i)
          hidbuf[(wbase + s*16 + quad*4 + i)*40 + c2*16 + n16] = (__bf16)fmaxf(hc[i], 0.f);
      }
    LDS_FENCE();   // hidden writes -> A-frag reads, cross-lane

    // ---- MLP2, both strips ----
    #pragma unroll
    for (int s = 0; s < 2; ++s) {
      const bf16x8 ha = *(const bf16x8*)&hidbuf[(wbase + s*16 + n16)*40 + quad*8];
      const f32x4 b2init = {b2ln, b2ln, b2ln, b2ln};
      const f32x4 ls = MFMA(ha, W2f, b2init);
      if (n16 < 4) {
        #pragma unroll
        for (int i = 0; i < 4; ++i)
          ((float*)&hidbuf[(wbase + s*16 + quad*4 + i)*40 + 32])[n16] = ls[i];
      }
    }
    LDS_FENCE();   // ls pad writes -> epilogue reads, cross-lane

    // ---- epilogue: all 64 lanes (strip x comp x row) ----
    {
      const float* lsp = (const float*)&hidbuf[erow*40 + 32];
      const float lc = lsp[comp];
      const float l2 = lsp[2 + comp];
      const float sv = __logf(1.0f + __expf(l2)) + 0.001f;
      yc += lc + sv * xt;
      lad += __logf(sv);
      ystate[erow*2 + comp] = yc;
      yp[t*2] = yc;
    }
    LDS_FENCE();   // ystate writes -> next-t gate reads, cross-lane
  }

  // lad: combine comps (partner lane^16 has same row, other comp)
  const float lado = __shfl(lad, lane ^ 16, 64);
  if (((lane >> 4) & 1) == 0)
    lad_out[gb + wbase + es*16 + (lane & 15)] = lad + lado;
}

extern "C" void kernel_launch(void* const* d_in, const int* in_sizes, int n_in,
                              void* d_out, int out_size, void* d_ws, size_t ws_size,
                              hipStream_t stream) {
  const float* x    = (const float*)d_in[0];
  const float* z    = (const float*)d_in[1];
  const float* W_ih = (const float*)d_in[2];
  const float* W_hh = (const float*)d_in[3];
  const float* b_ih = (const float*)d_in[4];
  const float* b_hh = (const float*)d_in[5];
  const float* W1   = (const float*)d_in[6];
  const float* b1   = (const float*)d_in[7];
  const float* W2   = (const float*)d_in[8];
  const float* b2   = (const float*)d_in[9];

  float* y_out   = (float*)d_out;
  float* lad_out = y_out + (size_t)BSZ * TT * 2;

  dim3 grid(BSZ / RPB), block(BLK);
  hipLaunchKernelGGL(flow8, grid, block, 0, stream,
                     x, z, W_ih, W_hh, b_ih, b_hh, W1, b1, W2, b2,
                     y_out, lad_out);
}

// Round 9
// 245.184 us; speedup vs baseline: 2.1416x; 1.2620x over previous
//
#include <hip/hip_runtime.h>

// B=131072, T=16, D=2, H=64. 16 rows/wave, 4 waves/block.
// R9 = R5 structure (Whr in regs, z/n+W1 frags in LDS, pre-scaled exp2 gates)
//  - hst fp32 register array DELETED: u*h carry reads old h from hbuf (bf16, same lane/addr)
//    -> arch demand ~68, unified ~112 <= 128  => bounds(256,4): 16 waves/CU, no spill
//  - LDS_FENCE at every cross-lane LDS handoff (R7 correctness lesson)
// LDS: 16384+4096+3072+9216+5120+512 = 38400 B; x4 blocks = 153.6 KB <= 160 KB.
#define BSZ 131072
#define TT  16
#define RPB 64
#define BLK 256

#define NEG_LOG2E  (-1.4426950408889634f)
#define TWO_LOG2E  2.8853900817779268f

typedef __bf16 bf16x8 __attribute__((ext_vector_type(8)));
typedef float  f32x4  __attribute__((ext_vector_type(4)));

#define MFMA(a,b,c) __builtin_amdgcn_mfma_f32_16x16x32_bf16((a),(b),(c),0,0,0)
// Compiler-level memory barrier: pins ordering of cross-lane LDS handoffs.
#define LDS_FENCE() asm volatile("" ::: "memory")

static __device__ __forceinline__ float rcp_f(float v){ float r; asm("v_rcp_f32 %0, %1" : "=v"(r) : "v"(v)); return r; }
static __device__ __forceinline__ float exp2_f(float v){ float r; asm("v_exp_f32 %0, %1" : "=v"(r) : "v"(v)); return r; }

__global__ __launch_bounds__(BLK, 4) void flow9(
    const float* __restrict__ x,     // (B,16,2)
    const float* __restrict__ z,     // (B,64)
    const float* __restrict__ W_ih,  // (192,2)
    const float* __restrict__ W_hh,  // (192,64)
    const float* __restrict__ b_ih,  // (192)
    const float* __restrict__ b_hh,  // (192)
    const float* __restrict__ W1,    // (64,32)
    const float* __restrict__ b1,    // (32)
    const float* __restrict__ W2,    // (32,4)
    const float* __restrict__ b2,    // (4)
    float* __restrict__ y_out,       // (B,16,2)
    float* __restrict__ lad_out)     // (B)
{
  __shared__ __align__(16) __bf16 whhtab[16*64*8];  // z/n-gate B-frags [f][lane][8] (pre-scaled)
  __shared__ __align__(16) __bf16 w1tab[4*64*8];    // W1 B-frags
  __shared__ __align__(16) float4 gi_tab[192];      // {Wih0*sc, Wih1*sc, bias*sc, 0}
  __shared__ __align__(16) __bf16 hbuf[RPB*72];     // h bf16, stride 72 (also the h carry!)
  __shared__ __align__(16) __bf16 hidbuf[RPB*40];   // hidden, stride 40; cols 32..39 = ls pad
  __shared__ __align__(16) float  ystate[RPB*2];    // y_{t-1} [row][comp]

  const int tid  = threadIdx.x;
  const int lane = tid & 63, wave = tid >> 6;
  const int quad = lane >> 4, n16 = lane & 15;
  const int gb   = blockIdx.x * RPB;
  const f32x4 zero = {0.f,0.f,0.f,0.f};

  // ---------- one-time staging ----------
  if (tid < 192) {  // gi_tab, pre-scaled; r/z bias in .z (applied in fma chain), n bias in .z
    const int j = tid;
    const float sc = (j < 128) ? NEG_LOG2E : TWO_LOG2E;
    const float w0 = W_ih[2*j]*sc, w1 = W_ih[2*j+1]*sc;
    const float bi = b_ih[j], bh = b_hh[j];
    gi_tab[j] = make_float4(w0, w1, ((j < 128) ? bi + bh : bi)*sc, 0.f);
  }
  // whhtab: f = (gate-1)*8 + g*2 + kt, gate 1=z (x -log2e), 2=n (x 2log2e)
  #pragma unroll
  for (int i = 0; i < 4; ++i) {
    const int f = i*4 + wave;
    const int gate = 1 + (f >> 3), g = (f >> 1) & 3, kt = f & 1;
    const float sc = (gate == 1) ? NEG_LOG2E : TWO_LOG2E;
    const float* p = W_hh + (size_t)((gate*4 + g)*16 + n16)*64 + kt*32 + quad*8;
    bf16x8 v;
    #pragma unroll
    for (int j = 0; j < 8; ++j) v[j] = (__bf16)(p[j]*sc);
    *(bf16x8*)&whhtab[(f*64 + lane)*8] = v;
  }
  { // w1tab: frag f = c2*2+kt = wave (unscaled)
    const int f = wave, c2 = f >> 1, kt = f & 1;
    bf16x8 v;
    #pragma unroll
    for (int j = 0; j < 8; ++j)
      v[j] = (__bf16)W1[(size_t)(kt*32 + quad*8 + j)*32 + c2*16 + n16];
    *(bf16x8*)&w1tab[(f*64 + lane)*8] = v;
  }
  if (tid < 128) ystate[tid] = 0.f;
  #pragma unroll
  for (int r4 = 0; r4 < 4; ++r4) {  // z -> hbuf (bf16)
    const int row = (tid >> 4) + r4*16, col = (tid & 15)*4;
    const float4 zv = *(const float4*)&z[(size_t)(gb + row)*64 + col];
    hbuf[row*72 + col+0] = (__bf16)zv.x; hbuf[row*72 + col+1] = (__bf16)zv.y;
    hbuf[row*72 + col+2] = (__bf16)zv.z; hbuf[row*72 + col+3] = (__bf16)zv.w;
  }

  // r-gate B-frags in regs (pre-scaled by -log2e): 8 x bf16x8 = 32 VGPR
  bf16x8 Whr[4][2];
  #pragma unroll
  for (int g = 0; g < 4; ++g)
    #pragma unroll
    for (int kt = 0; kt < 2; ++kt) {
      const float* p = W_hh + (size_t)(g*16 + n16)*64 + kt*32 + quad*8;
      bf16x8 v;
      #pragma unroll
      for (int j = 0; j < 8; ++j) v[j] = (__bf16)(p[j]*NEG_LOG2E);
      Whr[g][kt] = v;
    }
  // W2 B-frag in regs (4 VGPR)
  bf16x8 W2f;
  #pragma unroll
  for (int j = 0; j < 8; ++j)
    W2f[j] = (n16 < 4) ? (__bf16)W2[(size_t)(quad*8 + j)*4 + n16] : (__bf16)0.f;

  // NO fp32 hst array: h carry lives in hbuf (bf16) — read back per element.
  float bhn[4];   // b_hh n-part, scaled (cn C-init)
  #pragma unroll
  for (int g = 0; g < 4; ++g) bhn[g] = b_hh[128 + g*16 + n16]*TWO_LOG2E;
  const float b1v0 = b1[n16], b1v1 = b1[16 + n16];
  const float b2ln = (n16 < 4) ? b2[n16] : 0.f;

  __syncthreads();  // only block barrier

  const int arow = wave*16 + n16;
  bf16x8 a0 = *(const bf16x8*)&hbuf[arow*72 + quad*8];
  bf16x8 a1 = *(const bf16x8*)&hbuf[arow*72 + 32 + quad*8];

  const int erow = wave*16 + (lane & 15);
  const int comp = (lane >> 4) & 1;
  const float* xp = x + (size_t)(gb + erow)*(TT*2) + comp;
  float*       yp = y_out + (size_t)(gb + erow)*(TT*2) + comp;
  float yc = 0.f, lad = 0.f;

  #pragma unroll 1
  for (int t = 0; t < TT; ++t) {
    const float xt = (lane < 32) ? xp[t*2] : 0.f;   // early global load
    float ys0[4], ys1[4];
    #pragma unroll
    for (int i = 0; i < 4; ++i) {
      const float2 yv = *(const float2*)&ystate[(wave*16 + quad*4 + i)*2];
      ys0[i] = yv.x; ys1[i] = yv.y;
    }

    // ---- GRU per col-group g ----
    #pragma unroll
    for (int g = 0; g < 4; ++g) {
      const bf16x8 bz0 = *(const bf16x8*)&whhtab[((g*2    )*64 + lane)*8];
      const bf16x8 bz1 = *(const bf16x8*)&whhtab[((g*2 + 1)*64 + lane)*8];
      const bf16x8 bn0 = *(const bf16x8*)&whhtab[((8 + g*2    )*64 + lane)*8];
      const bf16x8 bn1 = *(const bf16x8*)&whhtab[((8 + g*2 + 1)*64 + lane)*8];
      f32x4 cr = MFMA(a0, Whr[g][0], zero); cr = MFMA(a1, Whr[g][1], cr);
      f32x4 cz = MFMA(a0, bz0, zero);       cz = MFMA(a1, bz1, cz);
      const f32x4 cninit = {bhn[g], bhn[g], bhn[g], bhn[g]};
      f32x4 cn = MFMA(a0, bn0, cninit);     cn = MFMA(a1, bn1, cn);
      const float4 Tr = gi_tab[      g*16 + n16];
      const float4 Tz = gi_tab[ 64 + g*16 + n16];
      const float4 Tn = gi_tab[128 + g*16 + n16];
      #pragma unroll
      for (int i = 0; i < 4; ++i) {
        const int haddr = (wave*16 + quad*4 + i)*72 + g*16 + n16;
        const float hold = (float)hbuf[haddr];      // old h (bf16 carry), read before write
        const float sr  = fmaf(Tr.x, ys0[i], fmaf(Tr.y, ys1[i], Tr.z)) + cr[i]; // -log2e*vr
        const float sz  = fmaf(Tz.x, ys0[i], fmaf(Tz.y, ys1[i], Tz.z)) + cz[i]; // -log2e*vz
        const float gin = fmaf(Tn.x, ys0[i], fmaf(Tn.y, ys1[i], Tn.z));         // 2log2e*i_n
        const float r  = rcp_f(1.0f + exp2_f(sr));
        const float u  = rcp_f(1.0f + exp2_f(sz));
        const float pre = fmaf(r, cn[i], gin);                                  // 2log2e*vn
        const float nn = fmaf(-2.0f, rcp_f(1.0f + exp2_f(pre)), 1.0f);          // tanh(vn)
        const float hv = fmaf(u, hold - nn, nn);
        hbuf[haddr] = (__bf16)hv;
      }
    }
    LDS_FENCE();   // gate writes (C-layout) -> A-frag reads, cross-lane

    a0 = *(const bf16x8*)&hbuf[arow*72 + quad*8];
    a1 = *(const bf16x8*)&hbuf[arow*72 + 32 + quad*8];

    // ---- MLP1 ----
    #pragma unroll
    for (int c2 = 0; c2 < 2; ++c2) {
      const float bb = c2 ? b1v1 : b1v0;
      const f32x4 binit = {bb, bb, bb, bb};
      f32x4 hc = MFMA(a0, *(const bf16x8*)&w1tab[((c2*2  )*64 + lane)*8], binit);
      hc       = MFMA(a1, *(const bf16x8*)&w1tab[((c2*2+1)*64 + lane)*8], hc);
      #pragma unroll
      for (int i = 0; i < 4; ++i)
        hidbuf[(wave*16 + quad*4 + i)*40 + c2*16 + n16] = (__bf16)fmaxf(hc[i], 0.f);
    }
    LDS_FENCE();   // hidden writes -> A-frag read, cross-lane

    // ---- MLP2: ls -> hidbuf pad (cols 32..39 as 4 floats) ----
    {
      const bf16x8 ha = *(const bf16x8*)&hidbuf[arow*40 + quad*8];
      const f32x4 b2init = {b2ln, b2ln, b2ln, b2ln};
      const f32x4 ls = MFMA(ha, W2f, b2init);
      if (n16 < 4) {
        #pragma unroll
        for (int i = 0; i < 4; ++i)
          ((float*)&hidbuf[(wave*16 + quad*4 + i)*40 + 32])[n16] = ls[i];
      }
    }
    LDS_FENCE();   // ls pad writes -> epilogue reads, cross-lane

    // ---- epilogue (32 lanes), direct global y store ----
    if (lane < 32) {
      const float* lsp = (const float*)&hidbuf[erow*40 + 32];
      const float lc = lsp[comp];
      const float l2 = lsp[2 + comp];
      const float s  = __logf(1.0f + __expf(l2)) + 0.001f;
      yc += lc + s * xt;
      lad += __logf(s);
      ystate[erow*2 + comp] = yc;
      yp[t*2] = yc;
    }
    LDS_FENCE();   // ystate writes -> next-t gate reads, cross-lane
  }

  const float lado = __shfl(lad, lane ^ 16, 64);
  if (lane < 16) lad_out[gb + wave*16 + lane] = lad + lado;
}

extern "C" void kernel_launch(void* const* d_in, const int* in_sizes, int n_in,
                              void* d_out, int out_size, void* d_ws, size_t ws_size,
                              hipStream_t stream) {
  const float* x    = (const float*)d_in[0];
  const float* z    = (const float*)d_in[1];
  const float* W_ih = (const float*)d_in[2];
  const float* W_hh = (const float*)d_in[3];
  const float* b_ih = (const float*)d_in[4];
  const float* b_hh = (const float*)d_in[5];
  const float* W1   = (const float*)d_in[6];
  const float* b1   = (const float*)d_in[7];
  const float* W2   = (const float*)d_in[8];
  const float* b2   = (const float*)d_in[9];

  float* y_out   = (float*)d_out;
  float* lad_out = y_out + (size_t)BSZ * TT * 2;

  dim3 grid(BSZ / RPB), block(BLK);
  hipLaunchKernelGGL(flow9, grid, block, 0, stream,
                     x, z, W_ih, W_hh, b_ih, b_hh, W1, b1, W2, b2,
                     y_out, lad_out);
}